// Round 6
// baseline (233.009 us; speedup 1.0000x reference)
//
#include <hip/hip_runtime.h>
#include <math.h>

#define N_NODES 50000
#define N_EDGES 800000
#define DIM 64
#define NPB 128
#define NPB_SHIFT 7
#define NBUCKET ((N_NODES + NPB - 1) >> NPB_SHIFT)     // 391
#define EPB 2048                                        // edges per partition/hist block
#define NBLK ((N_EDGES + EPB - 1) / EPB)                // 391

// ---- bf16 helpers (RNE) ----
__device__ __forceinline__ ushort f2bf(float x) {
    unsigned b = __float_as_uint(x);
    return (ushort)((b + 0x7FFFu + ((b >> 16) & 1u)) >> 16);
}
__device__ __forceinline__ float bf2f(ushort u) {
    return __uint_as_float(((unsigned)u) << 16);
}

// ============================== node GEMM ==============================
// zb = bf16(h @ W^T), zi = h @ U^T, s_src[n] = z[n].A[0:64], s_dst[n] = z[n].A[64:128]
// Thread (rb=tid>>4, cb=tid&15) owns rows {rb+16p}, cols {cb+16q}; k-loop in float4
// chunks so all LDS reads are ds_read_b128 (stride 68 rows: 16B-aligned, <=2-way alias).
__global__ __launch_bounds__(256) void node_linear(
    const float* __restrict__ h, const float* __restrict__ W,
    const float* __restrict__ U, const float* __restrict__ A,
    ushort* __restrict__ zb, float* __restrict__ zi,
    float* __restrict__ s_src, float* __restrict__ s_dst)
{
    __shared__ float Ws[DIM][68];
    __shared__ float Us[DIM][68];
    __shared__ float hs[64][68];

    const int tid = threadIdx.x;
    const int row0 = blockIdx.x * 64;

    for (int i = tid; i < 1024; i += 256) {
        int r = i >> 4, c = (i & 15) * 4;
        float4 w4 = ((const float4*)W)[i];
        float4 u4 = ((const float4*)U)[i];
        *(float4*)&Ws[r][c] = w4;
        *(float4*)&Us[r][c] = u4;
        int n = row0 + r;
        float4 h4 = (n < N_NODES) ? ((const float4*)h)[((size_t)n * DIM + c) >> 2]
                                  : make_float4(0.f, 0.f, 0.f, 0.f);
        *(float4*)&hs[r][c] = h4;
    }
    __syncthreads();

    const int rb = tid >> 4;    // 0..15, rows rb+16p
    const int cb = tid & 15;    // 0..15, cols cb+16q

    float accz[4][4] = {{0}}, accu[4][4] = {{0}};
    #pragma unroll 2
    for (int k = 0; k < DIM; k += 4) {
        float4 hv[4], wv[4], uv[4];
        #pragma unroll
        for (int p = 0; p < 4; ++p) hv[p] = *(const float4*)&hs[rb + 16 * p][k];
        #pragma unroll
        for (int q = 0; q < 4; ++q) {
            wv[q] = *(const float4*)&Ws[cb + 16 * q][k];
            uv[q] = *(const float4*)&Us[cb + 16 * q][k];
        }
        #pragma unroll
        for (int p = 0; p < 4; ++p)
            #pragma unroll
            for (int q = 0; q < 4; ++q) {
                accz[p][q] += hv[p].x * wv[q].x; accz[p][q] += hv[p].y * wv[q].y;
                accz[p][q] += hv[p].z * wv[q].z; accz[p][q] += hv[p].w * wv[q].w;
                accu[p][q] += hv[p].x * uv[q].x; accu[p][q] += hv[p].y * uv[q].y;
                accu[p][q] += hv[p].z * uv[q].z; accu[p][q] += hv[p].w * uv[q].w;
            }
    }

    float asrc[4], adst[4];
    #pragma unroll
    for (int q = 0; q < 4; ++q) { asrc[q] = A[cb + 16 * q]; adst[q] = A[DIM + cb + 16 * q]; }

    float ps[4], pd[4];
    #pragma unroll
    for (int p = 0; p < 4; ++p) {
        int n = row0 + rb + 16 * p;
        if (n < N_NODES) {
            #pragma unroll
            for (int q = 0; q < 4; ++q) {
                zb[(size_t)n * DIM + cb + 16 * q] = f2bf(accz[p][q]);
                zi[(size_t)n * DIM + cb + 16 * q] = accu[p][q];
            }
        }
        float s = 0.f, t = 0.f;
        #pragma unroll
        for (int q = 0; q < 4; ++q) { s += accz[p][q] * asrc[q]; t += accz[p][q] * adst[q]; }
        ps[p] = s; pd[p] = t;
    }
    #pragma unroll
    for (int m = 1; m < 16; m <<= 1) {
        #pragma unroll
        for (int p = 0; p < 4; ++p) {
            ps[p] += __shfl_xor(ps[p], m, 64);
            pd[p] += __shfl_xor(pd[p], m, 64);
        }
    }
    if ((tid & 15) == 0) {
        #pragma unroll
        for (int p = 0; p < 4; ++p) {
            int n = row0 + rb + 16 * p;
            if (n < N_NODES) { s_src[n] = ps[p]; s_dst[n] = pd[p]; }
        }
    }
}

// ============================== CSR build (bucketed) ==============================
// 1) per-block bucket histograms (no global atomics, no zero-init needed)
// 2) 1-block reduce+scan -> bbase/gcursor  3) partition into exclusive bucket ranges
// 4) per-bucket LDS counting sort -> edata (packed) + rowptr

__global__ __launch_bounds__(256) void bucket_hist(const int* __restrict__ dst, int* __restrict__ bh)
{
    __shared__ int h[NBUCKET];
    for (int b = threadIdx.x; b < NBUCKET; b += 256) h[b] = 0;
    __syncthreads();
    int base = blockIdx.x * EPB;
    #pragma unroll
    for (int j = 0; j < EPB / 256; ++j) {
        int e = base + j * 256 + threadIdx.x;
        if (e < N_EDGES) atomicAdd(&h[dst[e] >> NPB_SHIFT], 1);
    }
    __syncthreads();
    for (int b = threadIdx.x; b < NBUCKET; b += 256)
        bh[blockIdx.x * NBUCKET + b] = h[b];
}

__global__ __launch_bounds__(512) void bucket_scan(const int* __restrict__ bh,
                                                   int* __restrict__ bbase, int* __restrict__ gcursor)
{
    __shared__ int tmp[512];
    int t = threadIdx.x;
    int v = 0;
    if (t < NBUCKET)
        for (int blk = 0; blk < NBLK; ++blk) v += bh[blk * NBUCKET + t];
    tmp[t] = v;
    __syncthreads();
    for (int off = 1; off < 512; off <<= 1) {
        int a = (t >= off) ? tmp[t - off] : 0;
        __syncthreads();
        tmp[t] += a;
        __syncthreads();
    }
    int excl = tmp[t] - v;
    if (t < NBUCKET) { bbase[t] = excl; gcursor[t] = excl; }
    if (t == NBUCKET) bbase[t] = excl;   // == N_EDGES
}

// part[pos] = { (dstLocal<<16)|src , fp32 dval } into bucket-exclusive ranges
__global__ __launch_bounds__(256) void partition_kernel(
    const int* __restrict__ src, const int* __restrict__ dst, const float* __restrict__ dfeat,
    int* __restrict__ gcursor, int2* __restrict__ part)
{
    __shared__ int h[NBUCKET];
    for (int b = threadIdx.x; b < NBUCKET; b += 256) h[b] = 0;
    __syncthreads();
    int base = blockIdx.x * EPB;
    #pragma unroll
    for (int j = 0; j < EPB / 256; ++j) {
        int e = base + j * 256 + threadIdx.x;
        if (e < N_EDGES) atomicAdd(&h[dst[e] >> NPB_SHIFT], 1);
    }
    __syncthreads();
    // reserve: h[b] becomes this block's global write cursor for bucket b
    for (int b = threadIdx.x; b < NBUCKET; b += 256) {
        int v = h[b];
        h[b] = v ? atomicAdd(&gcursor[b], v) : 0;
    }
    __syncthreads();
    #pragma unroll
    for (int j = 0; j < EPB / 256; ++j) {
        int e = base + j * 256 + threadIdx.x;
        if (e < N_EDGES) {
            int d = dst[e];
            int pos = atomicAdd(&h[d >> NPB_SHIFT], 1);
            part[pos] = make_int2(((d & (NPB - 1)) << 16) | src[e], __float_as_int(dfeat[e]));
        }
    }
}

// one block per bucket: counting sort by local dst; emit edata=(src<<16)|bf16(dval), rowptr
__global__ __launch_bounds__(256) void bucket_sort(
    const int2* __restrict__ part, const int* __restrict__ bbase,
    unsigned* __restrict__ edata, int* __restrict__ rowptr)
{
    __shared__ int cnt[NPB];
    __shared__ int cur[NPB];
    int b = blockIdx.x, t = threadIdx.x;
    int beg = bbase[b], end = bbase[b + 1];
    if (t < NPB) cnt[t] = 0;
    __syncthreads();
    for (int i = beg + t; i < end; i += 256) atomicAdd(&cnt[part[i].x >> 16], 1);
    __syncthreads();
    if (t < NPB) cur[t] = cnt[t];
    __syncthreads();
    for (int off = 1; off < NPB; off <<= 1) {
        int a = (t < NPB && t >= off) ? cur[t - off] : 0;
        __syncthreads();
        if (t < NPB) cur[t] += a;
        __syncthreads();
    }
    int n0 = b << NPB_SHIFT;
    if (t < NPB) {
        int excl = cur[t] - cnt[t];
        int n = n0 + t;
        if (n < N_NODES) rowptr[n] = beg + excl;
        cur[t] = beg + excl;
    }
    if (b == NBUCKET - 1 && t == 0) rowptr[N_NODES] = N_EDGES;
    __syncthreads();
    for (int i = beg + t; i < end; i += 256) {
        int2 ed = part[i];
        int loc = ed.x >> 16;
        int pos = atomicAdd(&cur[loc], 1);
        edata[pos] = ((unsigned)(ed.x & 0xFFFF) << 16) | (unsigned)f2bf(__int_as_float(ed.y));
    }
}

// ============================== fused GAT ==============================
// wave per node; 4 groups x 16 lanes; group g gathers a full 128B z-row (ushort4/lane)
__global__ __launch_bounds__(256) void gat_fused(
    const int* __restrict__ rowptr, const unsigned* __restrict__ edata,
    const float* __restrict__ s_src, const float* __restrict__ s_dst,
    const ushort* __restrict__ zb, const float* __restrict__ zi,
    const float* __restrict__ V, const float* __restrict__ A,
    float* __restrict__ out)
{
    int n = blockIdx.x * 4 + (threadIdx.x >> 6);
    int lane = threadIdx.x & 63;
    int g = lane >> 4, q = lane & 15;
    if (n >= N_NODES) return;

    int beg = rowptr[n], end = rowptr[n + 1];
    if (beg == end) {
        if (lane < 16) ((float4*)out)[(size_t)n * 16 + q] = make_float4(0.f, 0.f, 0.f, 0.f);
        return;
    }

    float vae = V[0] * A[2 * DIM];
    float sd = s_dst[n];

    float l = 0.f;
    float4 a0 = make_float4(0.f, 0.f, 0.f, 0.f);
    float4 a1 = make_float4(0.f, 0.f, 0.f, 0.f);

    for (int c0 = beg; c0 < end; c0 += 64) {
        int c = c0 + lane;
        bool valid = c < end;
        unsigned w = valid ? edata[c] : 0u;
        int s = (int)(w >> 16);
        float dv = bf2f((ushort)(w & 0xFFFFu));
        float e = s_src[s] + sd + dv * vae;
        e = (e >= 0.f) ? e : 0.01f * e;
        float ex = valid ? __expf(e) : 0.f;

        float cs = ex;
        #pragma unroll
        for (int off = 32; off >= 1; off >>= 1) cs += __shfl_xor(cs, off, 64);
        l += cs;

        int cnt = min(64, end - c0);
        for (int k = 0; k < cnt; k += 8) {
            int i0 = k + g, i1 = k + 4 + g;      // always <= 63
            float e0 = __shfl(ex, i0, 64); if (i0 >= cnt) e0 = 0.f;
            float e1 = __shfl(ex, i1, 64); if (i1 >= cnt) e1 = 0.f;
            int s0 = __shfl(s, i0, 64);
            int s1 = __shfl(s, i1, 64);
            ushort4 v0 = *(const ushort4*)&zb[((size_t)s0 << 6) + (q << 2)];
            ushort4 v1 = *(const ushort4*)&zb[((size_t)s1 << 6) + (q << 2)];
            a0.x += e0 * bf2f(v0.x); a0.y += e0 * bf2f(v0.y);
            a0.z += e0 * bf2f(v0.z); a0.w += e0 * bf2f(v0.w);
            a1.x += e1 * bf2f(v1.x); a1.y += e1 * bf2f(v1.y);
            a1.z += e1 * bf2f(v1.z); a1.w += e1 * bf2f(v1.w);
        }
    }
    a0.x += a1.x; a0.y += a1.y; a0.z += a1.z; a0.w += a1.w;
    #pragma unroll
    for (int off = 16; off <= 32; off <<= 1) {
        a0.x += __shfl_xor(a0.x, off, 64);
        a0.y += __shfl_xor(a0.y, off, 64);
        a0.z += __shfl_xor(a0.z, off, 64);
        a0.w += __shfl_xor(a0.w, off, 64);
    }
    if (lane < 16) {
        float inv = 1.f / l;
        float4 z4 = ((const float4*)zi)[(size_t)n * 16 + q];
        float4 o;
        o.x = fmaxf(z4.x + a0.x * inv, 0.f);
        o.y = fmaxf(z4.y + a0.y * inv, 0.f);
        o.z = fmaxf(z4.z + a0.z * inv, 0.f);
        o.w = fmaxf(z4.w + a0.w * inv, 0.f);
        ((float4*)out)[(size_t)n * 16 + q] = o;
    }
}

// ============================== driver ==============================
static void run_layer(const float* h, const float* V, const float* W, const float* U, const float* A,
                      const int* rowptr, const unsigned* edata,
                      ushort* zb, float* zi, float* ssrc, float* sdst,
                      float* out, hipStream_t stream)
{
    node_linear<<<(N_NODES + 63) / 64, 256, 0, stream>>>(h, W, U, A, zb, zi, ssrc, sdst);
    gat_fused<<<(N_NODES + 3) / 4, 256, 0, stream>>>(rowptr, edata, ssrc, sdst, zb, zi, V, A, out);
}

extern "C" void kernel_launch(void* const* d_in, const int* in_sizes, int n_in,
                              void* d_out, int out_size, void* d_ws, size_t ws_size,
                              hipStream_t stream)
{
    const float* h  = (const float*)d_in[0];
    const float* dd = (const float*)d_in[1];
    const int* src  = (const int*)d_in[2];
    const int* dst  = (const int*)d_in[3];
    const float* V0 = (const float*)d_in[4];
    const float* W0 = (const float*)d_in[5];
    const float* U0 = (const float*)d_in[6];
    const float* A0 = (const float*)d_in[7];
    const float* V1 = (const float*)d_in[8];
    const float* W1 = (const float*)d_in[9];
    const float* U1 = (const float*)d_in[10];
    const float* A1 = (const float*)d_in[11];

    const size_t ND = (size_t)N_NODES * DIM;   // 3.2M
    float* ws     = (float*)d_ws;
    ushort* zb    = (ushort*)ws;                   // ND ushort = ND/2 float slots
    float* zi     = ws + ND / 2;                   // ND
    float* h1     = zi + ND;                       // ND
    float* ssrc   = h1 + ND;                       // N
    float* sdst   = ssrc + N_NODES;                // N
    int2*  part   = (int2*)(sdst + N_NODES);       // E int2 (8B aligned)
    unsigned* edata = (unsigned*)(part + N_EDGES); // E
    int*   bh     = (int*)(edata + N_EDGES);       // NBLK*NBUCKET (~612 KB)
    int*   bbase  = bh + NBLK * NBUCKET;           // NBUCKET+1
    int*   gcursor= bbase + NBUCKET + 1;           // NBUCKET
    int*   rowptr = gcursor + NBUCKET;             // N+1
    float* out    = (float*)d_out;

    // ---- CSR build (once; shared by both layers) ----
    bucket_hist<<<NBLK, 256, 0, stream>>>(dst, bh);
    bucket_scan<<<1, 512, 0, stream>>>(bh, bbase, gcursor);
    partition_kernel<<<NBLK, 256, 0, stream>>>(src, dst, dd, gcursor, part);
    bucket_sort<<<NBUCKET, 256, 0, stream>>>(part, bbase, edata, rowptr);

    // ---- two GAT layers ----
    run_layer(h,  V0, W0, U0, A0, rowptr, edata, zb, zi, ssrc, sdst, h1,  stream);
    run_layer(h1, V1, W1, U1, A1, rowptr, edata, zb, zi, ssrc, sdst, out, stream);
}

// Round 7
// 227.079 us; speedup vs baseline: 1.0261x; 1.0261x over previous
//
#include <hip/hip_runtime.h>
#include <math.h>

#define N_NODES 50000
#define N_EDGES 800000
#define DIM 64
#define NPB 128
#define NPB_SHIFT 7
#define NBUCKET ((N_NODES + NPB - 1) >> NPB_SHIFT)     // 391
#define EPB 2048                                        // edges per partition/hist block
#define NBLK ((N_EDGES + EPB - 1) / EPB)                // 391

// ---- bf16 helpers (RNE) ----
__device__ __forceinline__ ushort f2bf(float x) {
    unsigned b = __float_as_uint(x);
    return (ushort)((b + 0x7FFFu + ((b >> 16) & 1u)) >> 16);
}
__device__ __forceinline__ float bf2f(ushort u) {
    return __uint_as_float(((unsigned)u) << 16);
}

// ============================== node GEMM ==============================
// zb = bf16(h @ W^T), zi = h @ U^T, s_src[n] = z[n].A[0:64], s_dst[n] = z[n].A[64:128]
// (R5 version: 4x4 contiguous micro-tile, vector stores — measured best.)
__global__ __launch_bounds__(256) void node_linear(
    const float* __restrict__ h, const float* __restrict__ W,
    const float* __restrict__ U, const float* __restrict__ A,
    ushort* __restrict__ zb, float* __restrict__ zi,
    float* __restrict__ s_src, float* __restrict__ s_dst)
{
    __shared__ float Ws[DIM][DIM + 1];
    __shared__ float Us[DIM][DIM + 1];
    __shared__ float hs[64][DIM + 1];

    const int tid = threadIdx.x;
    const int row0 = blockIdx.x * 64;

    for (int i = tid; i < 1024; i += 256) {
        int r = i >> 4, c = (i & 15) * 4;
        float4 w4 = ((const float4*)W)[i];
        float4 u4 = ((const float4*)U)[i];
        Ws[r][c] = w4.x; Ws[r][c + 1] = w4.y; Ws[r][c + 2] = w4.z; Ws[r][c + 3] = w4.w;
        Us[r][c] = u4.x; Us[r][c + 1] = u4.y; Us[r][c + 2] = u4.z; Us[r][c + 3] = u4.w;
        int n = row0 + r;
        float4 h4 = (n < N_NODES) ? ((const float4*)h)[((size_t)n * DIM + c) >> 2]
                                  : make_float4(0.f, 0.f, 0.f, 0.f);
        hs[r][c] = h4.x; hs[r][c + 1] = h4.y; hs[r][c + 2] = h4.z; hs[r][c + 3] = h4.w;
    }
    __syncthreads();

    const int rb = (tid >> 4) * 4;
    const int cb = (tid & 15) * 4;

    float accz[4][4] = {{0}}, accu[4][4] = {{0}};
    #pragma unroll 8
    for (int k = 0; k < DIM; ++k) {
        float hv[4], wv[4], uv[4];
        #pragma unroll
        for (int r = 0; r < 4; ++r) hv[r] = hs[rb + r][k];
        #pragma unroll
        for (int c = 0; c < 4; ++c) { wv[c] = Ws[cb + c][k]; uv[c] = Us[cb + c][k]; }
        #pragma unroll
        for (int r = 0; r < 4; ++r)
            #pragma unroll
            for (int c = 0; c < 4; ++c) {
                accz[r][c] += hv[r] * wv[c];
                accu[r][c] += hv[r] * uv[c];
            }
    }

    float asrc[4], adst[4];
    #pragma unroll
    for (int c = 0; c < 4; ++c) { asrc[c] = A[cb + c]; adst[c] = A[DIM + cb + c]; }

    float ps[4], pd[4];
    #pragma unroll
    for (int r = 0; r < 4; ++r) {
        int n = row0 + rb + r;
        if (n < N_NODES) {
            ushort4 vz;
            vz.x = f2bf(accz[r][0]); vz.y = f2bf(accz[r][1]);
            vz.z = f2bf(accz[r][2]); vz.w = f2bf(accz[r][3]);
            *(ushort4*)&zb[(size_t)n * DIM + cb] = vz;
            float4 vu = make_float4(accu[r][0], accu[r][1], accu[r][2], accu[r][3]);
            *(float4*)&zi[(size_t)n * DIM + cb] = vu;
        }
        float s = 0.f, t = 0.f;
        #pragma unroll
        for (int c = 0; c < 4; ++c) { s += accz[r][c] * asrc[c]; t += accz[r][c] * adst[c]; }
        ps[r] = s; pd[r] = t;
    }
    #pragma unroll
    for (int m = 1; m < 16; m <<= 1) {
        #pragma unroll
        for (int r = 0; r < 4; ++r) {
            ps[r] += __shfl_xor(ps[r], m, 64);
            pd[r] += __shfl_xor(pd[r], m, 64);
        }
    }
    if ((tid & 15) == 0) {
        #pragma unroll
        for (int r = 0; r < 4; ++r) {
            int n = row0 + rb + r;
            if (n < N_NODES) { s_src[n] = ps[r]; s_dst[n] = pd[r]; }
        }
    }
}

// ============================== CSR build (bucketed) ==============================
__global__ __launch_bounds__(256) void bucket_hist(const int* __restrict__ dst, int* __restrict__ bh)
{
    __shared__ int h[NBUCKET];
    for (int b = threadIdx.x; b < NBUCKET; b += 256) h[b] = 0;
    __syncthreads();
    int base = blockIdx.x * EPB;
    #pragma unroll
    for (int j = 0; j < EPB / 256; ++j) {
        int e = base + j * 256 + threadIdx.x;
        if (e < N_EDGES) atomicAdd(&h[dst[e] >> NPB_SHIFT], 1);
    }
    __syncthreads();
    for (int b = threadIdx.x; b < NBUCKET; b += 256)
        bh[blockIdx.x * NBUCKET + b] = h[b];
}

__global__ __launch_bounds__(512) void bucket_scan(const int* __restrict__ bh,
                                                   int* __restrict__ bbase, int* __restrict__ gcursor)
{
    __shared__ int tmp[512];
    int t = threadIdx.x;
    int v = 0;
    if (t < NBUCKET)
        for (int blk = 0; blk < NBLK; ++blk) v += bh[blk * NBUCKET + t];
    tmp[t] = v;
    __syncthreads();
    for (int off = 1; off < 512; off <<= 1) {
        int a = (t >= off) ? tmp[t - off] : 0;
        __syncthreads();
        tmp[t] += a;
        __syncthreads();
    }
    int excl = tmp[t] - v;
    if (t < NBUCKET) { bbase[t] = excl; gcursor[t] = excl; }
    if (t == NBUCKET) bbase[t] = excl;   // == N_EDGES
}

__global__ __launch_bounds__(256) void partition_kernel(
    const int* __restrict__ src, const int* __restrict__ dst, const float* __restrict__ dfeat,
    int* __restrict__ gcursor, int2* __restrict__ part)
{
    __shared__ int h[NBUCKET];
    for (int b = threadIdx.x; b < NBUCKET; b += 256) h[b] = 0;
    __syncthreads();
    int base = blockIdx.x * EPB;
    #pragma unroll
    for (int j = 0; j < EPB / 256; ++j) {
        int e = base + j * 256 + threadIdx.x;
        if (e < N_EDGES) atomicAdd(&h[dst[e] >> NPB_SHIFT], 1);
    }
    __syncthreads();
    for (int b = threadIdx.x; b < NBUCKET; b += 256) {
        int v = h[b];
        h[b] = v ? atomicAdd(&gcursor[b], v) : 0;
    }
    __syncthreads();
    #pragma unroll
    for (int j = 0; j < EPB / 256; ++j) {
        int e = base + j * 256 + threadIdx.x;
        if (e < N_EDGES) {
            int d = dst[e];
            int pos = atomicAdd(&h[d >> NPB_SHIFT], 1);
            part[pos] = make_int2(((d & (NPB - 1)) << 16) | src[e], __float_as_int(dfeat[e]));
        }
    }
}

__global__ __launch_bounds__(256) void bucket_sort(
    const int2* __restrict__ part, const int* __restrict__ bbase,
    unsigned* __restrict__ edata, int* __restrict__ rowptr)
{
    __shared__ int cnt[NPB];
    __shared__ int cur[NPB];
    int b = blockIdx.x, t = threadIdx.x;
    int beg = bbase[b], end = bbase[b + 1];
    if (t < NPB) cnt[t] = 0;
    __syncthreads();
    for (int i = beg + t; i < end; i += 256) atomicAdd(&cnt[part[i].x >> 16], 1);
    __syncthreads();
    if (t < NPB) cur[t] = cnt[t];
    __syncthreads();
    for (int off = 1; off < NPB; off <<= 1) {
        int a = (t < NPB && t >= off) ? cur[t - off] : 0;
        __syncthreads();
        if (t < NPB) cur[t] += a;
        __syncthreads();
    }
    int n0 = b << NPB_SHIFT;
    if (t < NPB) {
        int excl = cur[t] - cnt[t];
        int n = n0 + t;
        if (n < N_NODES) rowptr[n] = beg + excl;
        cur[t] = beg + excl;
    }
    if (b == NBUCKET - 1 && t == 0) rowptr[N_NODES] = N_EDGES;
    __syncthreads();
    for (int i = beg + t; i < end; i += 256) {
        int2 ed = part[i];
        int loc = ed.x >> 16;
        int pos = atomicAdd(&cur[loc], 1);
        edata[pos] = ((unsigned)(ed.x & 0xFFFF) << 16) | (unsigned)f2bf(__int_as_float(ed.y));
    }
}

// ============================== fused GAT ==============================
// GROUP-PER-NODE: 16-lane group owns one node (4 nodes per wave, 16 per block).
// Softmax at full lane utilization; gather: each wave-instruction loads 4 z-rows.
__global__ __launch_bounds__(256) void gat_fused(
    const int* __restrict__ rowptr, const unsigned* __restrict__ edata,
    const float* __restrict__ s_src, const float* __restrict__ s_dst,
    const ushort* __restrict__ zb, const float* __restrict__ zi,
    const float* __restrict__ V, const float* __restrict__ A,
    float* __restrict__ out)
{
    const int n = blockIdx.x * 16 + (threadIdx.x >> 4);   // 50000 = 16*3125, no tail
    const int q = threadIdx.x & 15;                        // lane within group
    const int gbase = threadIdx.x & 48;                    // group base within wave

    int beg = rowptr[n], end = rowptr[n + 1];
    size_t orow = (size_t)n * 16 + q;                      // float4 index
    if (beg == end) {
        ((float4*)out)[orow] = make_float4(0.f, 0.f, 0.f, 0.f);
        return;
    }

    float vae = V[0] * A[2 * DIM];
    float sd = s_dst[n];

    float l = 0.f;
    float4 a0 = make_float4(0.f, 0.f, 0.f, 0.f);
    float4 a1 = make_float4(0.f, 0.f, 0.f, 0.f);

    for (int c0 = beg; c0 < end; c0 += 16) {
        int c = c0 + q;
        bool valid = c < end;
        unsigned w = valid ? edata[c] : 0u;
        int s = (int)(w >> 16);
        float dv = bf2f((ushort)(w & 0xFFFFu));
        float e = s_src[s] + sd + dv * vae;
        e = (e >= 0.f) ? e : 0.01f * e;
        float ex = valid ? __expf(e) : 0.f;

        float cs = ex;
        #pragma unroll
        for (int off = 8; off >= 1; off >>= 1) cs += __shfl_xor(cs, off, 16);
        l += cs;

        int cnt = min(16, end - c0);
        for (int k = 0; k < cnt; k += 4) {
            float e0 = __shfl(ex, gbase + k,     64); if (k     >= cnt) e0 = 0.f;
            float e1 = __shfl(ex, gbase + k + 1, 64); if (k + 1 >= cnt) e1 = 0.f;
            float e2 = __shfl(ex, gbase + k + 2, 64); if (k + 2 >= cnt) e2 = 0.f;
            float e3 = __shfl(ex, gbase + k + 3, 64); if (k + 3 >= cnt) e3 = 0.f;
            int s0 = __shfl(s, gbase + k,     64);
            int s1 = __shfl(s, gbase + k + 1, 64);
            int s2 = __shfl(s, gbase + k + 2, 64);
            int s3 = __shfl(s, gbase + k + 3, 64);
            ushort4 v0 = *(const ushort4*)&zb[((size_t)s0 << 6) + (q << 2)];
            ushort4 v1 = *(const ushort4*)&zb[((size_t)s1 << 6) + (q << 2)];
            ushort4 v2 = *(const ushort4*)&zb[((size_t)s2 << 6) + (q << 2)];
            ushort4 v3 = *(const ushort4*)&zb[((size_t)s3 << 6) + (q << 2)];
            a0.x += e0 * bf2f(v0.x); a0.y += e0 * bf2f(v0.y);
            a0.z += e0 * bf2f(v0.z); a0.w += e0 * bf2f(v0.w);
            a1.x += e1 * bf2f(v1.x); a1.y += e1 * bf2f(v1.y);
            a1.z += e1 * bf2f(v1.z); a1.w += e1 * bf2f(v1.w);
            a0.x += e2 * bf2f(v2.x); a0.y += e2 * bf2f(v2.y);
            a0.z += e2 * bf2f(v2.z); a0.w += e2 * bf2f(v2.w);
            a1.x += e3 * bf2f(v3.x); a1.y += e3 * bf2f(v3.y);
            a1.z += e3 * bf2f(v3.z); a1.w += e3 * bf2f(v3.w);
        }
    }
    float inv = 1.f / l;
    float4 z4 = ((const float4*)zi)[orow];
    float4 o;
    o.x = fmaxf(z4.x + (a0.x + a1.x) * inv, 0.f);
    o.y = fmaxf(z4.y + (a0.y + a1.y) * inv, 0.f);
    o.z = fmaxf(z4.z + (a0.z + a1.z) * inv, 0.f);
    o.w = fmaxf(z4.w + (a0.w + a1.w) * inv, 0.f);
    ((float4*)out)[orow] = o;
}

// ============================== driver ==============================
static void run_layer(const float* h, const float* V, const float* W, const float* U, const float* A,
                      const int* rowptr, const unsigned* edata,
                      ushort* zb, float* zi, float* ssrc, float* sdst,
                      float* out, hipStream_t stream)
{
    node_linear<<<(N_NODES + 63) / 64, 256, 0, stream>>>(h, W, U, A, zb, zi, ssrc, sdst);
    gat_fused<<<(N_NODES + 15) / 16, 256, 0, stream>>>(rowptr, edata, ssrc, sdst, zb, zi, V, A, out);
}

extern "C" void kernel_launch(void* const* d_in, const int* in_sizes, int n_in,
                              void* d_out, int out_size, void* d_ws, size_t ws_size,
                              hipStream_t stream)
{
    const float* h  = (const float*)d_in[0];
    const float* dd = (const float*)d_in[1];
    const int* src  = (const int*)d_in[2];
    const int* dst  = (const int*)d_in[3];
    const float* V0 = (const float*)d_in[4];
    const float* W0 = (const float*)d_in[5];
    const float* U0 = (const float*)d_in[6];
    const float* A0 = (const float*)d_in[7];
    const float* V1 = (const float*)d_in[8];
    const float* W1 = (const float*)d_in[9];
    const float* U1 = (const float*)d_in[10];
    const float* A1 = (const float*)d_in[11];

    const size_t ND = (size_t)N_NODES * DIM;   // 3.2M
    float* ws     = (float*)d_ws;
    ushort* zb    = (ushort*)ws;                   // ND ushort = ND/2 float slots
    float* zi     = ws + ND / 2;                   // ND
    float* h1     = zi + ND;                       // ND
    float* ssrc   = h1 + ND;                       // N
    float* sdst   = ssrc + N_NODES;                // N
    int2*  part   = (int2*)(sdst + N_NODES);       // E int2 (8B aligned)
    unsigned* edata = (unsigned*)(part + N_EDGES); // E
    int*   bh     = (int*)(edata + N_EDGES);       // NBLK*NBUCKET (~612 KB)
    int*   bbase  = bh + NBLK * NBUCKET;           // NBUCKET+1
    int*   gcursor= bbase + NBUCKET + 1;           // NBUCKET
    int*   rowptr = gcursor + NBUCKET;             // N+1
    float* out    = (float*)d_out;

    // ---- CSR build (once; shared by both layers) ----
    bucket_hist<<<NBLK, 256, 0, stream>>>(dst, bh);
    bucket_scan<<<1, 512, 0, stream>>>(bh, bbase, gcursor);
    partition_kernel<<<NBLK, 256, 0, stream>>>(src, dst, dd, gcursor, part);
    bucket_sort<<<NBUCKET, 256, 0, stream>>>(part, bbase, edata, rowptr);

    // ---- two GAT layers ----
    run_layer(h,  V0, W0, U0, A0, rowptr, edata, zb, zi, ssrc, sdst, h1,  stream);
    run_layer(h1, V1, W1, U1, A1, rowptr, edata, zb, zi, ssrc, sdst, out, stream);
}